// Round 1
// baseline (209.523 us; speedup 1.0000x reference)
//
#include <hip/hip_runtime.h>
#include <math.h>

#define HID 128
#define MROWS 1000
#define JROWS 5000
#define TILE_R 64
#define H0_STRIDE 132   // 128 + 4 pad: breaks 8-way LDS bank conflict, keeps 16B alignment (528B row)

// ---------------------------------------------------------------------------
// K1: precompute  g[128] = x_graph @ W0[0:256] + b0
//                 P[0:1000)   = x_m  @ W0[256:384]
//                 P[1000:6000)= x_job@ W0[384:512]
// ---------------------------------------------------------------------------
__global__ __launch_bounds__(128) void precompute_kernel(
    const float* __restrict__ x_graph,
    const float* __restrict__ x_m,
    const float* __restrict__ x_job,
    const float* __restrict__ W0,
    const float* __restrict__ b0,
    float* __restrict__ g,
    float* __restrict__ P)
{
    const int t = threadIdx.x;      // 0..127
    const int bid = blockIdx.x;

    if (bid == 0) {
        __shared__ float xg[2 * HID];
        xg[t] = x_graph[t];
        xg[t + HID] = x_graph[t + HID];
        __syncthreads();
        float acc = b0[t];
        #pragma unroll 8
        for (int k = 0; k < 2 * HID; ++k)
            acc = fmaf(xg[k], W0[k * HID + t], acc);
        g[t] = acc;
        return;
    }

    const int ablocks = (MROWS + 15) / 16;  // 63
    int nr, wbase;
    const float* src;
    float* dst;
    if (bid - 1 < ablocks) {
        int rb = (bid - 1) * 16;
        nr = min(16, MROWS - rb);
        wbase = 2 * HID;                    // W0 rows 256..383
        src = x_m + rb * HID;
        dst = P + rb * HID;
    } else {
        int rb = (bid - 1 - ablocks) * 16;
        nr = min(16, JROWS - rb);
        wbase = 3 * HID;                    // W0 rows 384..511
        src = x_job + rb * HID;
        dst = P + (MROWS + rb) * HID;
    }

    __shared__ float xs[16 * HID];
    for (int rr = 0; rr < 16; ++rr)
        xs[rr * HID + t] = (rr < nr) ? src[rr * HID + t] : 0.0f;
    __syncthreads();

    float acc[16];
    #pragma unroll
    for (int rr = 0; rr < 16; ++rr) acc[rr] = 0.0f;

    for (int k = 0; k < HID; ++k) {
        float w = W0[(wbase + k) * HID + t];
        #pragma unroll
        for (int rr = 0; rr < 16; ++rr)
            acc[rr] = fmaf(xs[rr * HID + k], w, acc[rr]);
    }
    for (int rr = 0; rr < nr; ++rr)
        dst[rr * HID + t] = acc[rr];
}

// ---------------------------------------------------------------------------
// K2: per 64-row tile: h0 = relu(g + P[m] + P[M+j]) (LDS),
//     h1 = relu(h0 @ W1 + b1), s = h1 @ W2 + b2,
//     block partial = (max, argmax[min-idx tie-break], Z=sum e^{s-max}, S=sum (s-max)e^{s-max})
// ---------------------------------------------------------------------------
#define FMA4(avc, wv)                         \
    acc[r][0] = fmaf(avc, wv.x, acc[r][0]);   \
    acc[r][1] = fmaf(avc, wv.y, acc[r][1]);   \
    acc[r][2] = fmaf(avc, wv.z, acc[r][2]);   \
    acc[r][3] = fmaf(avc, wv.w, acc[r][3]);

__global__ __launch_bounds__(256, 2) void main_kernel(
    const int* __restrict__ m_ids,
    const int* __restrict__ job_idx,
    const float* __restrict__ W1,
    const float* __restrict__ b1,
    const float* __restrict__ W2,
    const float* __restrict__ b2,
    const float* __restrict__ g,
    const float* __restrict__ P,
    float4* __restrict__ partials,
    int N)
{
    __shared__ float h0s[TILE_R * H0_STRIDE];
    __shared__ float sred[4 * TILE_R];

    const int t = threadIdx.x;
    const int row0 = blockIdx.x * TILE_R;

    // ---- stage h0 tile: thread t -> row t/4, column quarter t%4 ----
    {
        int row = t >> 2;
        int q = t & 3;
        int grow = row0 + row;
        int gr = (grow < N) ? grow : (N - 1);
        int m = m_ids[gr];
        int j = job_idx[gr];
        const float* pm = P + m * HID;
        const float* pj = P + (MROWS + j) * HID;
        #pragma unroll
        for (int u = 0; u < 8; ++u) {
            int c = q * 32 + u * 4;
            float4 vm = *(const float4*)(pm + c);
            float4 vj = *(const float4*)(pj + c);
            float4 vg = *(const float4*)(g + c);
            float4 h;
            h.x = fmaxf(vm.x + vj.x + vg.x, 0.0f);
            h.y = fmaxf(vm.y + vj.y + vg.y, 0.0f);
            h.z = fmaxf(vm.z + vj.z + vg.z, 0.0f);
            h.w = fmaxf(vm.w + vj.w + vg.w, 0.0f);
            *(float4*)&h0s[row * H0_STRIDE + c] = h;
        }
    }
    __syncthreads();

    // ---- register-tiled GEMM: wave w owns cols [w*32, w*32+32), all 64 rows ----
    const int w = t >> 6;           // wave 0..3
    const int l = t & 63;
    const int tc = l & 7;           // 8 col-groups per wave
    const int tr = l >> 3;          // 8 row-groups
    const int c0 = w * 32 + tc * 4;

    float4 b1v = *(const float4*)(b1 + c0);
    float4 w2v = *(const float4*)(W2 + c0);

    float acc[8][4];
    #pragma unroll
    for (int r = 0; r < 8; ++r)
        #pragma unroll
        for (int c = 0; c < 4; ++c) acc[r][c] = 0.0f;

    #pragma unroll 2
    for (int k0 = 0; k0 < HID; k0 += 4) {
        float4 w0v = *(const float4*)(W1 + (k0 + 0) * HID + c0);
        float4 w1v = *(const float4*)(W1 + (k0 + 1) * HID + c0);
        float4 w2m = *(const float4*)(W1 + (k0 + 2) * HID + c0);
        float4 w3v = *(const float4*)(W1 + (k0 + 3) * HID + c0);
        #pragma unroll
        for (int r = 0; r < 8; ++r) {
            float4 a = *(const float4*)&h0s[(tr * 8 + r) * H0_STRIDE + k0];
            FMA4(a.x, w0v)
            FMA4(a.y, w1v)
            FMA4(a.z, w2m)
            FMA4(a.w, w3v)
        }
    }

    // ---- epilogue: relu + b1, dot with W2, reduce over cols ----
    float p[8];
    #pragma unroll
    for (int r = 0; r < 8; ++r) {
        float h0v = fmaxf(acc[r][0] + b1v.x, 0.0f);
        float h1v = fmaxf(acc[r][1] + b1v.y, 0.0f);
        float h2v = fmaxf(acc[r][2] + b1v.z, 0.0f);
        float h3v = fmaxf(acc[r][3] + b1v.w, 0.0f);
        p[r] = h0v * w2v.x + h1v * w2v.y + h2v * w2v.z + h3v * w2v.w;
    }
    #pragma unroll
    for (int r = 0; r < 8; ++r) {
        p[r] += __shfl_xor(p[r], 1);
        p[r] += __shfl_xor(p[r], 2);
        p[r] += __shfl_xor(p[r], 4);
    }
    if (tc == 0) {
        #pragma unroll
        for (int r = 0; r < 8; ++r)
            sred[w * TILE_R + tr * 8 + r] = p[r];
    }
    __syncthreads();

    // ---- wave 0: per-block online-softmax partial over 64 rows ----
    if (t < 64) {
        int grow = row0 + t;
        float s = sred[t] + sred[64 + t] + sred[128 + t] + sred[192 + t] + b2[0];
        if (grow >= N) s = -1e30f;

        float mmax = s;
        int midx = grow;
        #pragma unroll
        for (int off = 1; off < 64; off <<= 1) {
            float om = __shfl_xor(mmax, off);
            int oi = __shfl_xor(midx, off);
            if (om > mmax || (om == mmax && oi < midx)) { mmax = om; midx = oi; }
        }
        float d = s - mmax;
        float e = expf(d);
        float z = e;
        float ss = d * e;
        #pragma unroll
        for (int off = 1; off < 64; off <<= 1) {
            z += __shfl_xor(z, off);
            ss += __shfl_xor(ss, off);
        }
        if (t == 0)
            partials[blockIdx.x] = make_float4(mmax, z, ss, (float)midx);
    }
}

// ---------------------------------------------------------------------------
// K3: merge block partials, emit (idx, probs[idx]=1/Z, logp[idx]=-logZ, H=logZ-S/Z)
// ---------------------------------------------------------------------------
__device__ inline void sm_merge(float& am, float& az, float& ass, int& ai,
                                float bm, float bz, float bss, int bi)
{
    if (bm > am || (bm == am && bi < ai)) {
        float tm = am, tz = az, ts = ass; int ti = ai;
        am = bm; az = bz; ass = bss; ai = bi;
        bm = tm; bz = tz; bss = ts; bi = ti;
    }
    float f = expf(bm - am);            // <= 1; empty sentinel -1e30 -> f=0, no NaN
    az += bz * f;
    ass += (bss + (bm - am) * bz) * f;
}

__global__ __launch_bounds__(256) void finalize_kernel(
    const float4* __restrict__ partials, int nparts, float* __restrict__ out)
{
    const int t = threadIdx.x;
    float m = -1e30f, z = 0.0f, ss = 0.0f;
    int idx = 0x7fffffff;

    for (int i = t; i < nparts; i += 256) {
        float4 p = partials[i];
        sm_merge(m, z, ss, idx, p.x, p.y, p.z, (int)p.w);
    }
    #pragma unroll
    for (int off = 1; off < 64; off <<= 1) {
        float om = __shfl_xor(m, off);
        float oz = __shfl_xor(z, off);
        float os = __shfl_xor(ss, off);
        int oi = __shfl_xor(idx, off);
        sm_merge(m, z, ss, idx, om, oz, os, oi);
    }
    __shared__ float4 wred[4];
    __shared__ int widx[4];
    if ((t & 63) == 0) { wred[t >> 6] = make_float4(m, z, ss, 0.0f); widx[t >> 6] = idx; }
    __syncthreads();
    if (t == 0) {
        for (int i = 1; i < 4; ++i)
            sm_merge(m, z, ss, idx, wred[i].x, wred[i].y, wred[i].z, widx[i]);
        float logZ = logf(z);
        out[0] = (float)idx;        // argmax (exact: idx < 2^24)
        out[1] = 1.0f / z;          // probs[idx]
        out[2] = -logZ;             // logp[idx]
        out[3] = logZ - ss / z;     // entropy
    }
}

// ---------------------------------------------------------------------------
extern "C" void kernel_launch(void* const* d_in, const int* in_sizes, int n_in,
                              void* d_out, int out_size, void* d_ws, size_t ws_size,
                              hipStream_t stream)
{
    const float* x_graph = (const float*)d_in[0];
    const float* x_m     = (const float*)d_in[1];
    const float* x_job   = (const float*)d_in[2];
    const int*   m_ids   = (const int*)d_in[3];
    const int*   job_idx = (const int*)d_in[4];
    const float* W0      = (const float*)d_in[5];
    const float* b0      = (const float*)d_in[6];
    const float* W1      = (const float*)d_in[7];
    const float* b1      = (const float*)d_in[8];
    const float* W2      = (const float*)d_in[9];
    const float* b2      = (const float*)d_in[10];
    float* out = (float*)d_out;

    const int N = in_sizes[3];              // 200000
    float* ws = (float*)d_ws;
    float* g = ws;                                          // 128 floats
    float* P = ws + HID;                                    // 6000*128 floats
    float4* partials = (float4*)(ws + HID + (MROWS + JROWS) * HID);  // 16B-aligned

    const int tiles = (N + TILE_R - 1) / TILE_R;            // 3125
    const int ablocks = (MROWS + 15) / 16;                  // 63
    const int bblocks = (JROWS + 15) / 16;                  // 313

    precompute_kernel<<<1 + ablocks + bblocks, 128, 0, stream>>>(
        x_graph, x_m, x_job, W0, b0, g, P);
    main_kernel<<<tiles, 256, 0, stream>>>(
        m_ids, job_idx, W1, b1, W2, b2, g, P, partials, N);
    finalize_kernel<<<1, 256, 0, stream>>>(partials, tiles, out);
}

// Round 2
// 197.827 us; speedup vs baseline: 1.0591x; 1.0591x over previous
//
#include <hip/hip_runtime.h>
#include <math.h>

#define HID 128
#define TILE_R 64
#define H0_STRIDE 132   // 128 + 4 pad; with row-interleaved lane map, GEMM reads are conflict-free:
                        // concurrent lanes (tr=0..7) read rows stride-1 apart = 132 floats = 4 banks apart,
                        // each ds_read_b128 covers 4 banks -> 8 lanes tile all 32 banks exactly.

#define FMA4(avc, wv)                         \
    acc[r][0] = fmaf(avc, wv.x, acc[r][0]);   \
    acc[r][1] = fmaf(avc, wv.y, acc[r][1]);   \
    acc[r][2] = fmaf(avc, wv.z, acc[r][2]);   \
    acc[r][3] = fmaf(avc, wv.w, acc[r][3]);

// ---------------------------------------------------------------------------
// K1: precompute  g[128] = x_graph @ W0[0:256] + b0      (block 0)
//                 P[0:M)   = x_m  @ W0[256:384]          (blocks 1 .. aTiles)
//                 P[M:M+J) = x_job@ W0[384:512]          (blocks aTiles+1 ..)
// Same register-tiled 64-row structure as main_kernel.
// ---------------------------------------------------------------------------
__global__ __launch_bounds__(256, 4) void precompute_kernel(
    const float* __restrict__ x_graph,
    const float* __restrict__ x_m,
    const float* __restrict__ x_job,
    const float* __restrict__ W0,
    const float* __restrict__ b0,
    float* __restrict__ g,
    float* __restrict__ P,
    int M, int J, int aTiles)
{
    const int t = threadIdx.x;
    const int bid = blockIdx.x;

    if (bid == 0) {
        // g = x_graph @ W0[0:256] + b0   (tiny: 32K FMA)
        __shared__ float xg[2 * HID];
        if (t < HID) { xg[t] = x_graph[t]; xg[t + HID] = x_graph[t + HID]; }
        __syncthreads();
        if (t < HID) {
            float acc = b0[t];
            #pragma unroll 8
            for (int k = 0; k < 2 * HID; ++k)
                acc = fmaf(xg[k], W0[k * HID + t], acc);
            g[t] = acc;
        }
        return;
    }

    const int tb = bid - 1;
    const float* X;
    const float* W;
    int r0, nr, dstBase;
    if (tb < aTiles) {
        r0 = tb * TILE_R;
        nr = min(TILE_R, M - r0);
        X = x_m + (size_t)r0 * HID;
        W = W0 + 2 * HID * HID;
        dstBase = r0;
    } else {
        int jb = tb - aTiles;
        r0 = jb * TILE_R;
        nr = min(TILE_R, J - r0);
        X = x_job + (size_t)r0 * HID;
        W = W0 + 3 * HID * HID;
        dstBase = M + r0;
    }

    __shared__ float xs[TILE_R * H0_STRIDE];
    {
        int row = t >> 2;
        int q = t & 3;
        #pragma unroll
        for (int u = 0; u < 8; ++u) {
            int c = q * 32 + u * 4;
            float4 v = (row < nr) ? *(const float4*)(X + row * HID + c)
                                  : make_float4(0.f, 0.f, 0.f, 0.f);
            *(float4*)&xs[row * H0_STRIDE + c] = v;
        }
    }
    __syncthreads();

    const int w = t >> 6;
    const int l = t & 63;
    const int tc = l & 7;
    const int tr = l >> 3;
    const int c0 = w * 32 + tc * 4;

    float acc[8][4];
    #pragma unroll
    for (int r = 0; r < 8; ++r)
        #pragma unroll
        for (int c = 0; c < 4; ++c) acc[r][c] = 0.0f;

    #pragma unroll 2
    for (int k0 = 0; k0 < HID; k0 += 4) {
        float4 w0v = *(const float4*)(W + (k0 + 0) * HID + c0);
        float4 w1v = *(const float4*)(W + (k0 + 1) * HID + c0);
        float4 w2m = *(const float4*)(W + (k0 + 2) * HID + c0);
        float4 w3v = *(const float4*)(W + (k0 + 3) * HID + c0);
        #pragma unroll
        for (int r = 0; r < 8; ++r) {
            float4 a = *(const float4*)&xs[(r * 8 + tr) * H0_STRIDE + k0];
            FMA4(a.x, w0v)
            FMA4(a.y, w1v)
            FMA4(a.z, w2m)
            FMA4(a.w, w3v)
        }
    }

    #pragma unroll
    for (int r = 0; r < 8; ++r) {
        int row = r * 8 + tr;
        if (row < nr)
            *(float4*)(P + (size_t)(dstBase + row) * HID + c0) =
                make_float4(acc[r][0], acc[r][1], acc[r][2], acc[r][3]);
    }
}

// ---------------------------------------------------------------------------
// K2: per 64-row tile: h0 = relu(g + P[m] + P[M+j]) (LDS),
//     h1 = relu(h0 @ W1 + b1), s = h1 @ W2 + b2,
//     block partial = (max, argmax[min-idx], Z=sum e^{s-max}, S=sum (s-max)e^{s-max})
// ---------------------------------------------------------------------------
__global__ __launch_bounds__(256, 4) void main_kernel(
    const int* __restrict__ m_ids,
    const int* __restrict__ job_idx,
    const float* __restrict__ W1,
    const float* __restrict__ b1,
    const float* __restrict__ W2,
    const float* __restrict__ b2,
    const float* __restrict__ g,
    const float* __restrict__ P,
    float4* __restrict__ partials,
    int N, int M)
{
    __shared__ float h0s[TILE_R * H0_STRIDE];
    __shared__ float sred[4 * TILE_R];

    const int t = threadIdx.x;
    const int row0 = blockIdx.x * TILE_R;

    // ---- stage h0 tile: thread t -> row t/4, column quarter t%4 ----
    {
        int row = t >> 2;
        int q = t & 3;
        int grow = row0 + row;
        int gr = (grow < N) ? grow : (N - 1);
        int m = m_ids[gr];
        int j = job_idx[gr];
        const float* pm = P + (size_t)m * HID;
        const float* pj = P + (size_t)(M + j) * HID;
        #pragma unroll
        for (int u = 0; u < 8; ++u) {
            int c = q * 32 + u * 4;
            float4 vm = *(const float4*)(pm + c);
            float4 vj = *(const float4*)(pj + c);
            float4 vg = *(const float4*)(g + c);
            float4 h;
            h.x = fmaxf(vm.x + vj.x + vg.x, 0.0f);
            h.y = fmaxf(vm.y + vj.y + vg.y, 0.0f);
            h.z = fmaxf(vm.z + vj.z + vg.z, 0.0f);
            h.w = fmaxf(vm.w + vj.w + vg.w, 0.0f);
            *(float4*)&h0s[row * H0_STRIDE + c] = h;
        }
    }
    __syncthreads();

    // ---- register-tiled GEMM: wave w owns cols [w*32, w*32+32), all 64 rows.
    //      Lane->row map interleaved (row = r*8+tr) for conflict-free LDS reads.
    const int w = t >> 6;
    const int l = t & 63;
    const int tc = l & 7;
    const int tr = l >> 3;
    const int c0 = w * 32 + tc * 4;

    float4 b1v = *(const float4*)(b1 + c0);
    float4 w2v = *(const float4*)(W2 + c0);

    float acc[8][4];
    #pragma unroll
    for (int r = 0; r < 8; ++r)
        #pragma unroll
        for (int c = 0; c < 4; ++c) acc[r][c] = 0.0f;

    #pragma unroll 2
    for (int k0 = 0; k0 < HID; k0 += 4) {
        float4 w0v = *(const float4*)(W1 + (k0 + 0) * HID + c0);
        float4 w1v = *(const float4*)(W1 + (k0 + 1) * HID + c0);
        float4 w2m = *(const float4*)(W1 + (k0 + 2) * HID + c0);
        float4 w3v = *(const float4*)(W1 + (k0 + 3) * HID + c0);
        #pragma unroll
        for (int r = 0; r < 8; ++r) {
            float4 a = *(const float4*)&h0s[(r * 8 + tr) * H0_STRIDE + k0];
            FMA4(a.x, w0v)
            FMA4(a.y, w1v)
            FMA4(a.z, w2m)
            FMA4(a.w, w3v)
        }
    }

    // ---- epilogue: relu + b1, dot with W2, reduce over the 8 col-groups ----
    float p[8];
    #pragma unroll
    for (int r = 0; r < 8; ++r) {
        float h0v = fmaxf(acc[r][0] + b1v.x, 0.0f);
        float h1v = fmaxf(acc[r][1] + b1v.y, 0.0f);
        float h2v = fmaxf(acc[r][2] + b1v.z, 0.0f);
        float h3v = fmaxf(acc[r][3] + b1v.w, 0.0f);
        p[r] = h0v * w2v.x + h1v * w2v.y + h2v * w2v.z + h3v * w2v.w;
    }
    #pragma unroll
    for (int r = 0; r < 8; ++r) {
        p[r] += __shfl_xor(p[r], 1);
        p[r] += __shfl_xor(p[r], 2);
        p[r] += __shfl_xor(p[r], 4);
    }
    if (tc == 0) {
        #pragma unroll
        for (int r = 0; r < 8; ++r)
            sred[w * TILE_R + r * 8 + tr] = p[r];
    }
    __syncthreads();

    // ---- wave 0: per-block online-softmax partial over 64 rows ----
    if (t < 64) {
        int grow = row0 + t;
        float s = sred[t] + sred[64 + t] + sred[128 + t] + sred[192 + t] + b2[0];
        if (grow >= N) s = -1e30f;

        float mmax = s;
        int midx = grow;
        #pragma unroll
        for (int off = 1; off < 64; off <<= 1) {
            float om = __shfl_xor(mmax, off);
            int oi = __shfl_xor(midx, off);
            if (om > mmax || (om == mmax && oi < midx)) { mmax = om; midx = oi; }
        }
        float d = s - mmax;
        float e = expf(d);
        float z = e;
        float ss = d * e;
        #pragma unroll
        for (int off = 1; off < 64; off <<= 1) {
            z += __shfl_xor(z, off);
            ss += __shfl_xor(ss, off);
        }
        if (t == 0)
            partials[blockIdx.x] = make_float4(mmax, z, ss, (float)midx);
    }
}

// ---------------------------------------------------------------------------
// K3: merge block partials, emit (idx, probs[idx]=1/Z, logp[idx]=-logZ, H=logZ-S/Z)
// ---------------------------------------------------------------------------
__device__ inline void sm_merge(float& am, float& az, float& ass, int& ai,
                                float bm, float bz, float bss, int bi)
{
    if (bm > am || (bm == am && bi < ai)) {
        float tm = am, tz = az, ts = ass; int ti = ai;
        am = bm; az = bz; ass = bss; ai = bi;
        bm = tm; bz = tz; bss = ts; bi = ti;
    }
    float f = expf(bm - am);            // <= 1; empty sentinel -1e30 -> f=0, no NaN
    az += bz * f;
    ass += (bss + (bm - am) * bz) * f;
}

__global__ __launch_bounds__(256) void finalize_kernel(
    const float4* __restrict__ partials, int nparts, float* __restrict__ out)
{
    const int t = threadIdx.x;
    float m = -1e30f, z = 0.0f, ss = 0.0f;
    int idx = 0x7fffffff;

    for (int i = t; i < nparts; i += 256) {
        float4 p = partials[i];
        sm_merge(m, z, ss, idx, p.x, p.y, p.z, (int)p.w);
    }
    #pragma unroll
    for (int off = 1; off < 64; off <<= 1) {
        float om = __shfl_xor(m, off);
        float oz = __shfl_xor(z, off);
        float os = __shfl_xor(ss, off);
        int oi = __shfl_xor(idx, off);
        sm_merge(m, z, ss, idx, om, oz, os, oi);
    }
    __shared__ float4 wred[4];
    __shared__ int widx[4];
    if ((t & 63) == 0) { wred[t >> 6] = make_float4(m, z, ss, 0.0f); widx[t >> 6] = idx; }
    __syncthreads();
    if (t == 0) {
        for (int i = 1; i < 4; ++i)
            sm_merge(m, z, ss, idx, wred[i].x, wred[i].y, wred[i].z, widx[i]);
        float logZ = logf(z);
        out[0] = (float)idx;        // argmax (exact: idx < 2^24)
        out[1] = 1.0f / z;          // probs[idx]
        out[2] = -logZ;             // logp[idx]
        out[3] = logZ - ss / z;     // entropy
    }
}

// ---------------------------------------------------------------------------
extern "C" void kernel_launch(void* const* d_in, const int* in_sizes, int n_in,
                              void* d_out, int out_size, void* d_ws, size_t ws_size,
                              hipStream_t stream)
{
    const float* x_graph = (const float*)d_in[0];
    const float* x_m     = (const float*)d_in[1];
    const float* x_job   = (const float*)d_in[2];
    const int*   m_ids   = (const int*)d_in[3];
    const int*   job_idx = (const int*)d_in[4];
    const float* W0      = (const float*)d_in[5];
    const float* b0      = (const float*)d_in[6];
    const float* W1      = (const float*)d_in[7];
    const float* b1      = (const float*)d_in[8];
    const float* W2      = (const float*)d_in[9];
    const float* b2      = (const float*)d_in[10];
    float* out = (float*)d_out;

    const int N = in_sizes[3];
    const int M = in_sizes[1] / HID;
    const int J = in_sizes[2] / HID;

    float* ws = (float*)d_ws;
    float* g = ws;                                       // 128 floats
    float* P = ws + HID;                                 // (M+J)*128 floats
    float4* partials = (float4*)(ws + HID + (size_t)(M + J) * HID);

    const int tiles = (N + TILE_R - 1) / TILE_R;         // 3125
    const int aTiles = (M + TILE_R - 1) / TILE_R;        // 16
    const int bTiles = (J + TILE_R - 1) / TILE_R;        // 79

    precompute_kernel<<<1 + aTiles + bTiles, 256, 0, stream>>>(
        x_graph, x_m, x_job, W0, b0, g, P, M, J, aTiles);
    main_kernel<<<tiles, 256, 0, stream>>>(
        m_ids, job_idx, W1, b1, W2, b2, g, P, partials, N, M);
    finalize_kernel<<<1, 256, 0, stream>>>(partials, tiles, out);
}